// Round 1
// baseline (56.337 us; speedup 1.0000x reference)
//
#include <hip/hip_runtime.h>

// Problem constants (B,N,F) = (8, 4096, 256), fp32 in/out.
constexpr int B = 8;
constexpr int N = 4096;
constexpr int F = 256;
constexpr int F4 = F / 4;         // 64 float4 per row
constexpr int PARTS = 32;         // partial-sum blocks per batch
constexpr int RPP = N / PARTS;    // 128 rows per partial block

// --- Kernel 1: partial column sums of ref_flow: partial[b,p,:] = sum over rows [p*RPP,(p+1)*RPP) ---
__global__ void colsum_partial(const float* __restrict__ flow, float* __restrict__ partial) {
    const int b = blockIdx.x, p = blockIdx.y;
    const int c = threadIdx.x;   // float4 column 0..63
    const int ty = threadIdx.y;  // 0..3 row subgroup
    const float4* base = reinterpret_cast<const float4*>(flow) + ((size_t)b * N + (size_t)p * RPP) * F4;
    float4 acc = make_float4(0.f, 0.f, 0.f, 0.f);
    for (int r = ty; r < RPP; r += 4) {
        float4 v = base[(size_t)r * F4 + c];
        acc.x += v.x; acc.y += v.y; acc.z += v.z; acc.w += v.w;
    }
    __shared__ float4 red[4][64];
    red[ty][c] = acc;
    __syncthreads();
    if (ty == 0) {
        float4 a0 = red[0][c], a1 = red[1][c], a2 = red[2][c], a3 = red[3][c];
        float4 s = make_float4(a0.x + a1.x + a2.x + a3.x,
                               a0.y + a1.y + a2.y + a3.y,
                               a0.z + a1.z + a2.z + a3.z,
                               a0.w + a1.w + a2.w + a3.w);
        reinterpret_cast<float4*>(partial)[((size_t)b * PARTS + p) * F4 + c] = s;
    }
}

// --- Kernel 2: reduce partials -> S[b,:] (deterministic fixed-order sum) ---
__global__ void colsum_reduce(const float* __restrict__ partial, float* __restrict__ S) {
    const int b = blockIdx.x;
    const int c = threadIdx.x;  // 0..63
    float4 acc = make_float4(0.f, 0.f, 0.f, 0.f);
    for (int p = 0; p < PARTS; ++p) {
        float4 v = reinterpret_cast<const float4*>(partial)[((size_t)b * PARTS + p) * F4 + c];
        acc.x += v.x; acc.y += v.y; acc.z += v.z; acc.w += v.w;
    }
    reinterpret_cast<float4*>(S)[(size_t)b * F4 + c] = acc;
}

// --- Kernel 3/5: score[row] = dot(feat[row,:], vecs[batch(row),:]); one wave (64 lanes) per row ---
__global__ void row_dot(const float* __restrict__ feat, const float* __restrict__ vecs,
                        float* __restrict__ score) {
    const int wave = threadIdx.x >> 6;      // 4 waves per block
    const int lane = threadIdx.x & 63;
    const size_t row = (size_t)blockIdx.x * 4 + wave;  // global row in [0, B*N)
    const int b = (int)(row >> 12);         // row / N (N = 4096)
    float4 a = reinterpret_cast<const float4*>(feat)[row * F4 + lane];
    float4 w = reinterpret_cast<const float4*>(vecs)[(size_t)b * F4 + lane];
    float d = a.x * w.x + a.y * w.y + a.z * w.z + a.w * w.w;
    #pragma unroll
    for (int off = 32; off; off >>= 1) d += __shfl_down(d, off);
    if (lane == 0) score[row] = d;
}

// --- Kernel 4/6: iterative top-K (min or max, lower-index tie-break like jax.lax.top_k),
//     then gather rgb rows into out[b, OUT_ROW0+k, :]; optionally emit T = sum of selected flow rows ---
template <bool MIN, int K, int OUT_ROW0>
__global__ void topk_gather(const float* __restrict__ score, const float* __restrict__ rgb,
                            const float* __restrict__ flow, float* __restrict__ out,
                            float* __restrict__ T) {
    const int b = blockIdx.x;
    const int t = threadIdx.x;  // 256 threads
    __shared__ float sval[256];
    __shared__ int sidx[256];
    __shared__ int chosen[K];

    for (int k = 0; k < K; ++k) {
        float bestv = MIN ? INFINITY : -INFINITY;
        int besti = 0x7fffffff;
        for (int i = t; i < N; i += 256) {
            bool skip = false;
            for (int j = 0; j < k; ++j)
                if (chosen[j] == i) skip = true;
            if (skip) continue;
            float v = score[(size_t)b * N + i];
            bool better = MIN ? (v < bestv || (v == bestv && i < besti))
                              : (v > bestv || (v == bestv && i < besti));
            if (better) { bestv = v; besti = i; }
        }
        sval[t] = bestv;
        sidx[t] = besti;
        __syncthreads();
        for (int s = 128; s; s >>= 1) {
            if (t < s) {
                float ov = sval[t + s];
                int oi = sidx[t + s];
                bool better = MIN ? (ov < sval[t] || (ov == sval[t] && oi < sidx[t]))
                                  : (ov > sval[t] || (ov == sval[t] && oi < sidx[t]));
                if (better) { sval[t] = ov; sidx[t] = oi; }
            }
            __syncthreads();
        }
        if (t == 0) chosen[k] = sidx[0];
        __syncthreads();
    }

    // Gather: thread t = feature index (F == blockDim.x == 256)
    float tsum = 0.f;
    for (int k = 0; k < K; ++k) {
        const int idx = chosen[k];
        out[((size_t)b * 5 + OUT_ROW0 + k) * F + t] = rgb[((size_t)b * N + idx) * F + t];
        if (T) tsum += flow[((size_t)b * N + idx) * F + t];
    }
    if (T) T[(size_t)b * F + t] = tsum;
}

extern "C" void kernel_launch(void* const* d_in, const int* in_sizes, int n_in,
                              void* d_out, int out_size, void* d_ws, size_t ws_size,
                              hipStream_t stream) {
    const float* ref_rgb  = (const float*)d_in[0];
    const float* ref_flow = (const float*)d_in[1];
    const float* sup_rgb  = (const float*)d_in[2];
    const float* sup_flow = (const float*)d_in[3];
    float* out = (float*)d_out;  // (B, 5, F) fp32

    float* ws      = (float*)d_ws;
    float* partial = ws;                                  // B*PARTS*F
    float* S       = partial + (size_t)B * PARTS * F;     // B*F
    float* score1  = S + (size_t)B * F;                   // B*N
    float* Tv      = score1 + (size_t)B * N;              // B*F
    float* score2  = Tv + (size_t)B * F;                  // B*N

    // 1) S[b] = sum_n ref_flow[b,n,:]
    colsum_partial<<<dim3(B, PARTS), dim3(64, 4), 0, stream>>>(ref_flow, partial);
    colsum_reduce<<<B, 64, 0, stream>>>(partial, S);
    // 2) score1[b,n] = ref_flow[b,n]·S[b]  (ordering == mean over m of intra_sim)
    row_dot<<<(B * N) / 4, 256, 0, stream>>>(ref_flow, S, score1);
    // 3) 3 smallest -> out rows 0..2 (ref_rgb) + T[b] = sum of chosen ref_flow rows
    topk_gather<true, 3, 0><<<B, 256, 0, stream>>>(score1, ref_rgb, ref_flow, out, Tv);
    // 4) score2[b,m] = sup_flow[b,m]·T[b]
    row_dot<<<(B * N) / 4, 256, 0, stream>>>(sup_flow, Tv, score2);
    // 5) 2 largest -> out rows 3..4 (sup_rgb)
    topk_gather<false, 2, 3><<<B, 256, 0, stream>>>(score2, sup_rgb, nullptr, out, nullptr);
}

// Round 2
// 46.535 us; speedup vs baseline: 1.2106x; 1.2106x over previous
//
#include <hip/hip_runtime.h>
#include <math.h>

// (B,N,F) = (8, 4096, 256), fp32 in/out. out = (B, 5, F).
constexpr int B = 8;
constexpr int N = 4096;
constexpr int F = 256;
constexpr int F4 = F / 4;          // 64 float4 per row
constexpr int PARTS = 32;          // partial-sum blocks per batch
constexpr int RPP = N / PARTS;     // 128 rows per partial block
constexpr int CHUNKS = 64;         // dot/top-k chunk blocks per batch
constexpr int RPC = N / CHUNKS;    // 64 rows per chunk

// --- Kernel 1: partial column sums of ref_flow ---
__global__ void colsum_partial(const float* __restrict__ flow, float* __restrict__ partial) {
    const int b = blockIdx.x, p = blockIdx.y;
    const int c = threadIdx.x;   // float4 column 0..63
    const int ty = threadIdx.y;  // 0..3
    const float4* base = reinterpret_cast<const float4*>(flow) + ((size_t)b * N + (size_t)p * RPP) * F4;
    float4 acc = make_float4(0.f, 0.f, 0.f, 0.f);
    for (int r = ty; r < RPP; r += 4) {
        float4 v = base[(size_t)r * F4 + c];
        acc.x += v.x; acc.y += v.y; acc.z += v.z; acc.w += v.w;
    }
    __shared__ float4 red[4][64];
    red[ty][c] = acc;
    __syncthreads();
    if (ty == 0) {
        float4 a0 = red[0][c], a1 = red[1][c], a2 = red[2][c], a3 = red[3][c];
        float4 s = make_float4(a0.x + a1.x + a2.x + a3.x,
                               a0.y + a1.y + a2.y + a3.y,
                               a0.z + a1.z + a2.z + a3.z,
                               a0.w + a1.w + a2.w + a3.w);
        reinterpret_cast<float4*>(partial)[((size_t)b * PARTS + p) * F4 + c] = s;
    }
}

// --- Kernel 2: per chunk: reduce partials -> S, dot 64 rows, block-local top-3 (min) candidates ---
__global__ void dot1_top3(const float* __restrict__ flow, const float* __restrict__ partial,
                          float* __restrict__ cand_val, int* __restrict__ cand_idx) {
    const int b = blockIdx.x, chunk = blockIdx.y;
    const int t = threadIdx.x;            // 256 threads
    const int wave = t >> 6, lane = t & 63;
    __shared__ float S[F];
    __shared__ float score[RPC];
    __shared__ float sval[RPC];
    __shared__ int   sidx[RPC];

    // S[t] = sum_p partial[b][p][t]  (redundant per block; partials are L2-resident)
    float acc = 0.f;
    #pragma unroll
    for (int p = 0; p < PARTS; ++p) acc += partial[((size_t)b * PARTS + p) * F + t];
    S[t] = acc;
    __syncthreads();

    // dots: one wave per row
    float4 s4 = reinterpret_cast<const float4*>(S)[lane];
    const float4* rowbase = reinterpret_cast<const float4*>(flow) + ((size_t)b * N + (size_t)chunk * RPC) * F4;
    for (int r = wave; r < RPC; r += 4) {
        float4 a = rowbase[(size_t)r * F4 + lane];
        float d = a.x * s4.x + a.y * s4.y + a.z * s4.z + a.w * s4.w;
        #pragma unroll
        for (int off = 32; off; off >>= 1) d += __shfl_down(d, off);
        if (lane == 0) score[r] = d;
    }
    __syncthreads();

    // top-3 smallest of RPC scores (local idx tie-break == global order within chunk)
    for (int k = 0; k < 3; ++k) {
        if (t < RPC) { sval[t] = score[t]; sidx[t] = t; }
        __syncthreads();
        for (int s = RPC / 2; s; s >>= 1) {
            if (t < s) {
                float ov = sval[t + s]; int oi = sidx[t + s];
                if (ov < sval[t] || (ov == sval[t] && oi < sidx[t])) { sval[t] = ov; sidx[t] = oi; }
            }
            __syncthreads();
        }
        if (t == 0) {
            cand_val[(b * CHUNKS + chunk) * 3 + k] = sval[0];
            cand_idx[(b * CHUNKS + chunk) * 3 + k] = chunk * RPC + sidx[0];
            score[sidx[0]] = INFINITY;  // exclude for next round
        }
        __syncthreads();
    }
}

// --- Kernel 3: per chunk: merge 192 candidates -> top-3 (redundant per block), build Tv,
//     (chunk 0 writes out rows 0..2 from ref_rgb), dot 64 sup rows, block-local top-2 (max) ---
__global__ void dot2_top2(const float* __restrict__ sup_flow, const float* __restrict__ ref_flow,
                          const float* __restrict__ ref_rgb,
                          const float* __restrict__ cand_val, const int* __restrict__ cand_idx,
                          float* __restrict__ out,
                          float* __restrict__ cand2_val, int* __restrict__ cand2_idx) {
    const int b = blockIdx.x, chunk = blockIdx.y;
    const int t = threadIdx.x;            // 256
    const int wave = t >> 6, lane = t & 63;
    constexpr int NC = 3 * CHUNKS;        // 192 candidates, pad to 256 slots
    __shared__ float cval[256];
    __shared__ int   cgid[256];
    __shared__ float sval[256];
    __shared__ int   sgid[256];
    __shared__ int   chosen[3];
    __shared__ float Tv[F];
    __shared__ float score[RPC];

    cval[t] = (t < NC) ? cand_val[b * NC + t] : INFINITY;
    cgid[t] = (t < NC) ? cand_idx[b * NC + t] : 0x7fffffff;
    __syncthreads();

    // global top-3 smallest with global-index tie-break
    for (int k = 0; k < 3; ++k) {
        sval[t] = cval[t]; sgid[t] = cgid[t];
        __syncthreads();
        for (int s = 128; s; s >>= 1) {
            if (t < s) {
                float ov = sval[t + s]; int oi = sgid[t + s];
                if (ov < sval[t] || (ov == sval[t] && oi < sgid[t])) { sval[t] = ov; sgid[t] = oi; }
            }
            __syncthreads();
        }
        if (t == 0) chosen[k] = sgid[0];
        __syncthreads();
        if (cgid[t] == chosen[k]) cval[t] = INFINITY;
        __syncthreads();
    }

    const int i0 = chosen[0], i1 = chosen[1], i2 = chosen[2];
    // Tv[t] = sum of the 3 selected ref_flow rows (L3-resident reads)
    Tv[t] = ref_flow[((size_t)b * N + i0) * F + t]
          + ref_flow[((size_t)b * N + i1) * F + t]
          + ref_flow[((size_t)b * N + i2) * F + t];
    if (chunk == 0) {
        out[((size_t)b * 5 + 0) * F + t] = ref_rgb[((size_t)b * N + i0) * F + t];
        out[((size_t)b * 5 + 1) * F + t] = ref_rgb[((size_t)b * N + i1) * F + t];
        out[((size_t)b * 5 + 2) * F + t] = ref_rgb[((size_t)b * N + i2) * F + t];
    }
    __syncthreads();

    // dot2: one wave per sup row
    float4 s4 = reinterpret_cast<const float4*>(Tv)[lane];
    const float4* rowbase = reinterpret_cast<const float4*>(sup_flow) + ((size_t)b * N + (size_t)chunk * RPC) * F4;
    for (int r = wave; r < RPC; r += 4) {
        float4 a = rowbase[(size_t)r * F4 + lane];
        float d = a.x * s4.x + a.y * s4.y + a.z * s4.z + a.w * s4.w;
        #pragma unroll
        for (int off = 32; off; off >>= 1) d += __shfl_down(d, off);
        if (lane == 0) score[r] = d;
    }
    __syncthreads();

    // block-local top-2 largest
    for (int k = 0; k < 2; ++k) {
        if (t < RPC) { sval[t] = score[t]; sgid[t] = t; }
        __syncthreads();
        for (int s = RPC / 2; s; s >>= 1) {
            if (t < s) {
                float ov = sval[t + s]; int oi = sgid[t + s];
                if (ov > sval[t] || (ov == sval[t] && oi < sgid[t])) { sval[t] = ov; sgid[t] = oi; }
            }
            __syncthreads();
        }
        if (t == 0) {
            cand2_val[(b * CHUNKS + chunk) * 2 + k] = sval[0];
            cand2_idx[(b * CHUNKS + chunk) * 2 + k] = chunk * RPC + sgid[0];
            score[sgid[0]] = -INFINITY;
        }
        __syncthreads();
    }
}

// --- Kernel 4: per batch: merge 128 candidates -> top-2 largest, gather sup_rgb rows 3..4 ---
__global__ void final_top2(const float* __restrict__ cand2_val, const int* __restrict__ cand2_idx,
                           const float* __restrict__ sup_rgb, float* __restrict__ out) {
    const int b = blockIdx.x;
    const int t = threadIdx.x;  // 256
    constexpr int NC = 2 * CHUNKS;  // 128
    __shared__ float cval[NC];
    __shared__ int   cgid[NC];
    __shared__ float sval[NC];
    __shared__ int   sgid[NC];
    __shared__ int   chosen[2];

    if (t < NC) { cval[t] = cand2_val[b * NC + t]; cgid[t] = cand2_idx[b * NC + t]; }
    __syncthreads();

    for (int k = 0; k < 2; ++k) {
        if (t < NC) { sval[t] = cval[t]; sgid[t] = cgid[t]; }
        __syncthreads();
        for (int s = NC / 2; s; s >>= 1) {
            if (t < s) {
                float ov = sval[t + s]; int oi = sgid[t + s];
                if (ov > sval[t] || (ov == sval[t] && oi < sgid[t])) { sval[t] = ov; sgid[t] = oi; }
            }
            __syncthreads();
        }
        if (t == 0) chosen[k] = sgid[0];
        __syncthreads();
        if (t < NC && cgid[t] == chosen[k]) cval[t] = -INFINITY;
        __syncthreads();
    }

    out[((size_t)b * 5 + 3) * F + t] = sup_rgb[((size_t)b * N + chosen[0]) * F + t];
    out[((size_t)b * 5 + 4) * F + t] = sup_rgb[((size_t)b * N + chosen[1]) * F + t];
}

extern "C" void kernel_launch(void* const* d_in, const int* in_sizes, int n_in,
                              void* d_out, int out_size, void* d_ws, size_t ws_size,
                              hipStream_t stream) {
    const float* ref_rgb  = (const float*)d_in[0];
    const float* ref_flow = (const float*)d_in[1];
    const float* sup_rgb  = (const float*)d_in[2];
    const float* sup_flow = (const float*)d_in[3];
    float* out = (float*)d_out;  // (B, 5, F)

    float* ws        = (float*)d_ws;
    float* partial   = ws;                                      // B*PARTS*F = 65536
    float* cand_val  = partial + (size_t)B * PARTS * F;         // B*CHUNKS*3 = 1536
    float* cand2_val = cand_val + (size_t)B * CHUNKS * 3;       // B*CHUNKS*2 = 1024
    int*   cand_idx  = (int*)(cand2_val + (size_t)B * CHUNKS * 2);
    int*   cand2_idx = cand_idx + (size_t)B * CHUNKS * 3;

    colsum_partial<<<dim3(B, PARTS), dim3(64, 4), 0, stream>>>(ref_flow, partial);
    dot1_top3<<<dim3(B, CHUNKS), 256, 0, stream>>>(ref_flow, partial, cand_val, cand_idx);
    dot2_top2<<<dim3(B, CHUNKS), 256, 0, stream>>>(sup_flow, ref_flow, ref_rgb,
                                                   cand_val, cand_idx, out, cand2_val, cand2_idx);
    final_top2<<<B, 256, 0, stream>>>(cand2_val, cand2_idx, sup_rgb, out);
}